// Round 8
// baseline (262.479 us; speedup 1.0000x reference)
//
#include <hip/hip_runtime.h>
#include <cstdint>
#include <cstddef>

// Problem dims
#define NB 2
#define NTT 2048
#define ND 1024
#define NK 8
#define NF 4096
#define NTOK (NB*NTT)
#define LAMBDA_C 0.5f

// Output layout (float units)
#define Y_SZ   (NTOK*ND)
#define LG_OFF Y_SZ
#define SC_OFF (LG_OFF + NTOK*NK)
#define AD_OFF (SC_OFF + NK)

// Workspace layout (4-byte units)
#define WS_CNT    0
#define WS_SEG    8
#define WS_NTILES 17
#define WS_TILEK  32
#define WS_TILER  1056
#define WS_PTOK   4096
#define WS_PCOEF  36864
#define WS_COEF   69632
#define WS_X16    102400   // x as f16 (8MB)
#define WS_H      2199552  // f16 h buffer

#define BM 128
#define BN 128
#define BK 64
#define SPLITK2 4
#define KT 16

// LDS byte offsets: A dbuf 2x16KB, B dbuf 2x16KB
#define ASL0 0u
#define ASL1 16384u
#define BSL0 32768u
#define BSL1 49152u

typedef float  f32x4  __attribute__((ext_vector_type(4)));
typedef float  f32x16 __attribute__((ext_vector_type(16)));
typedef _Float16 f16x8 __attribute__((ext_vector_type(8)));
typedef unsigned int u32x4 __attribute__((ext_vector_type(4)));

__device__ __forceinline__ unsigned int pkrtz(float a, float b){
    auto h = __builtin_amdgcn_cvt_pkrtz(a, b);
    return __builtin_bit_cast(unsigned int, h);
}
__device__ __forceinline__ float gelu_exact(float v){
    return 0.5f * v * (1.0f + erff(v * 0.70710678118654752440f));
}

// ---------------- x -> f16 prepass ----------------
__global__ __launch_bounds__(256) void k_xcast(const float* __restrict__ x,
                                               unsigned short* __restrict__ x16)
{
    int i = (blockIdx.x*256 + threadIdx.x) * 16;
    const f32x4* src = (const f32x4*)(x + i);
    f32x4 v0 = src[0], v1 = src[1], v2 = src[2], v3 = src[3];
    u32x4 o0 = {pkrtz(v0[0],v0[1]), pkrtz(v0[2],v0[3]), pkrtz(v1[0],v1[1]), pkrtz(v1[2],v1[3])};
    u32x4 o1 = {pkrtz(v2[0],v2[1]), pkrtz(v2[2],v2[3]), pkrtz(v3[0],v3[1]), pkrtz(v3[2],v3[3])};
    *(u32x4*)(x16 + i)     = o0;
    *(u32x4*)(x16 + i + 8) = o1;
}

// ---------------- gating ----------------
__global__ __launch_bounds__(256) void k_gating(
    const float* __restrict__ x, const float* __restrict__ pl,
    const float* __restrict__ Wt, const float* __restrict__ Wgt,
    const float* __restrict__ Wel, float* __restrict__ out,
    float* __restrict__ coef, int* __restrict__ cnt)
{
    int t = blockIdx.x;
    const float* xt = x + (size_t)t * ND;
    float acc[NK] = {0,0,0,0,0,0,0,0};
    for (int d = threadIdx.x; d < ND; d += 256){
        float xv = xt[d];
        const float4* w = (const float4*)(Wt + (size_t)d * NK);
        float4 w0 = w[0], w1 = w[1];
        acc[0] += xv*w0.x; acc[1] += xv*w0.y; acc[2] += xv*w0.z; acc[3] += xv*w0.w;
        acc[4] += xv*w1.x; acc[5] += xv*w1.y; acc[6] += xv*w1.z; acc[7] += xv*w1.w;
    }
    __shared__ float red[4][NK];
    #pragma unroll
    for (int k = 0; k < NK; k++){
        float v = acc[k];
        #pragma unroll
        for (int off = 32; off; off >>= 1) v += __shfl_down(v, off);
        if ((threadIdx.x & 63) == 0) red[threadIdx.x >> 6][k] = v;
    }
    __syncthreads();
    if (threadIdx.x == 0){
        const float* p = pl + (size_t)t * NK;
        float pv[NK];
        #pragma unroll
        for (int j = 0; j < NK; j++) pv[j] = p[j];
        float lg[NK]; float mx = -1e30f;
        #pragma unroll
        for (int k = 0; k < NK; k++){
            float v = red[0][k] + red[1][k] + red[2][k] + red[3][k];
            #pragma unroll
            for (int j = 0; j < NK; j++) v += pv[j] * Wgt[j*NK + k];
            lg[k] = v; mx = fmaxf(mx, v);
            out[LG_OFF + (size_t)t*NK + k] = v;
        }
        float e[NK]; float s = 0.f;
        #pragma unroll
        for (int k = 0; k < NK; k++){ e[k] = expf(lg[k] - mx); s += e[k]; }
        float g[NK]; float gsum = 0.f;
        #pragma unroll
        for (int k = 0; k < NK; k++){
            float st = e[k] / s;
            float we = 1.f / (1.f + expf(-Wel[k]));
            bool m = st > LAMBDA_C * we;
            g[k] = m ? st : 0.f;
            gsum += g[k];
        }
        float inv = 1.f / (gsum + 1e-6f);
        #pragma unroll
        for (int k = 0; k < NK; k++){
            coef[(size_t)t*NK + k] = g[k] * inv;
            if (g[k] > 0.f) atomicAdd(&cnt[k], 1);
        }
    }
}

// ---------------- scan ----------------
__global__ __launch_bounds__(256) void k_scan(
    const float* __restrict__ coef, int* __restrict__ wsi,
    float* __restrict__ wsf, int pair_cap)
{
    int k = blockIdx.x;
    const int* cnt = wsi + WS_CNT;
    int base = 0;
    for (int j = 0; j < k; j++) base += cnt[j];
    int tid = threadIdx.x, lane = tid & 63, w = tid >> 6;
    __shared__ int wsum[4];
    __shared__ int sbase;
    if (tid == 0){
        sbase = base;
        wsi[WS_SEG + k] = base;
        if (k == NK-1) wsi[WS_SEG + NK] = base + cnt[k];
    }
    __syncthreads();
    int* ptok = wsi + WS_PTOK;
    float* pc = wsf + WS_PCOEF;
    for (int c0 = 0; c0 < NTOK; c0 += 256){
        int t = c0 + tid;
        float c = coef[(size_t)t*NK + k];
        bool m = c > 0.f;
        unsigned long long bal = __ballot(m);
        int pre = __popcll(bal & ((1ull << lane) - 1ull));
        if (lane == 0) wsum[w] = __popcll(bal);
        __syncthreads();
        int b = sbase;
        for (int j = 0; j < w; j++) b += wsum[j];
        if (m){
            int pos = b + pre;
            if (pos < pair_cap){ ptok[pos] = t; pc[pos] = c; }
        }
        __syncthreads();
        if (tid == 0) sbase += wsum[0] + wsum[1] + wsum[2] + wsum[3];
        __syncthreads();
    }
}

// ---------------- tiles + small outputs ----------------
__global__ void k_tiles(int* __restrict__ wsi, float* __restrict__ out, int pair_cap)
{
    if (threadIdx.x == 0 && blockIdx.x == 0){
        const int* cnt = wsi + WS_CNT;
        const int* seg = wsi + WS_SEG;
        int total = 0;
        for (int k = 0; k < NK; k++){ total += cnt[k]; out[SC_OFF + k] = (float)cnt[k]; }
        out[AD_OFF] = (float)total / (float)NTOK;
        int nt = 0;
        for (int k = 0; k < NK; k++){
            int e = min(seg[k+1], pair_cap);
            for (int r = seg[k]; r < e; r += BM){
                wsi[WS_TILEK + nt] = k; wsi[WS_TILER + nt] = r; nt++;
            }
        }
        wsi[WS_NTILES] = nt;
    }
}

// XCD-chunked bijective work partition
#define XCD_PART_LOOP(nwork)                                              \
    int q_ = (nwork) >> 3, rr_ = (nwork) & 7;                             \
    int xcd_ = blockIdx.x & 7;                                            \
    int slot_ = blockIdx.x >> 3;                                          \
    int nslot_ = gridDim.x >> 3;                                          \
    int cntw_ = q_ + (xcd_ < rr_ ? 1 : 0);                                \
    int start_ = xcd_ * q_ + (xcd_ < rr_ ? xcd_ : rr_);                   \
    for (int p_ = slot_; p_ < cntw_; p_ += nslot_)

// ---- shared GEMM building blocks ----
// B LDS: col c (0..127) at c*128B, k-octet u(0..7) 16B at (u*16)^(((c>>1)&7)<<4)
// A LDS: row r (0..127) at r*128B, 16B slot v at (v*16)^((r&7)<<4); filled by
//        global_load_lds with pre-swizzled per-lane SOURCE (LDS linear dest).

#define LOADB(tt_, LDW_)                                                  \
  { const float* bn_ = bsrc + (size_t)((tt_)*BK + bu*8)*(LDW_);           \
    _Pragma("unroll")                                                     \
    for (int r9_ = 0; r9_ < 8; r9_++) gb[r9_] = *(const f32x4*)(bn_ + (size_t)r9_*(LDW_)); }

#define CVTWRB(BO_)                                                       \
  { _Pragma("unroll")                                                     \
    for (int j9_ = 0; j9_ < 4; j9_++){                                    \
        unsigned p0_ = pkrtz(gb[0][j9_], gb[1][j9_]);                     \
        unsigned p1_ = pkrtz(gb[2][j9_], gb[3][j9_]);                     \
        unsigned p2_ = pkrtz(gb[4][j9_], gb[5][j9_]);                     \
        unsigned p3_ = pkrtz(gb[6][j9_], gb[7][j9_]);                     \
        unsigned c9_ = (unsigned)(bg*4 + j9_);                            \
        unsigned off9_ = (BO_) + c9_*128u + (((unsigned)bu*16u) ^ (((c9_>>1)&7u)<<4)); \
        *(u32x4*)(&lds[off9_]) = (u32x4){p0_, p1_, p2_, p3_};             \
    } }

#define GLL_A(AO_, tt_)                                                   \
  { _Pragma("unroll")                                                     \
    for (int c9_ = 0; c9_ < 4; c9_++){                                    \
        const unsigned short* g9_ = asrc[c9_] + (tt_)*BK + asw8;          \
        __builtin_amdgcn_global_load_lds(                                 \
            (const __attribute__((address_space(1))) void*)g9_,           \
            (__attribute__((address_space(3))) void*)(&lds[(AO_) + (unsigned)((wv*4 + c9_)*1024)]), \
            16, 0, 0);                                                    \
    } }

#define MFMA_PH(AO_, BO_)                                                 \
  { __builtin_amdgcn_s_setprio(1);                                        \
    _Pragma("unroll")                                                     \
    for (int s9_ = 0; s9_ < 4; s9_++){                                    \
        unsigned ko_ = (unsigned)(s9_*32) + ah16;                         \
        f16x8 a0_ = *(const f16x8*)(&lds[(AO_) + arow0*128u + (ko_ ^ axr)]); \
        f16x8 a1_ = *(const f16x8*)(&lds[(AO_) + arow1*128u + (ko_ ^ axr)]); \
        f16x8 b0_ = *(const f16x8*)(&lds[(BO_) + bcol0*128u + (ko_ ^ bxr)]); \
        f16x8 b1_ = *(const f16x8*)(&lds[(BO_) + bcol1*128u + (ko_ ^ bxr)]); \
        acc00 = __builtin_amdgcn_mfma_f32_32x32x16_f16(a0_, b0_, acc00, 0,0,0); \
        acc01 = __builtin_amdgcn_mfma_f32_32x32x16_f16(a0_, b1_, acc01, 0,0,0); \
        acc10 = __builtin_amdgcn_mfma_f32_32x32x16_f16(a1_, b0_, acc10, 0,0,0); \
        acc11 = __builtin_amdgcn_mfma_f32_32x32x16_f16(a1_, b1_, acc11, 0,0,0); \
    }                                                                     \
    __builtin_amdgcn_s_setprio(0); }

#define PIPE_LOOP(LDW_)                                                   \
    f32x16 acc00 = {0}, acc01 = {0}, acc10 = {0}, acc11 = {0};            \
    LOADB(0, LDW_)                                                        \
    GLL_A(ASL0, 0)                                                        \
    for (int t = 0; t < KT-1; t++){                                       \
        if ((t & 1) == 0){                                                \
            CVTWRB(BSL0)                                                  \
            LOADB(t+1, LDW_)                                              \
            asm volatile("s_waitcnt vmcnt(8) lgkmcnt(0)" ::: "memory");   \
            __builtin_amdgcn_s_barrier();                                 \
            __builtin_amdgcn_sched_barrier(0);                            \
            GLL_A(ASL1, t+1)                                              \
            MFMA_PH(ASL0, BSL0)                                           \
        } else {                                                          \
            CVTWRB(BSL1)                                                  \
            LOADB(t+1, LDW_)                                              \
            asm volatile("s_waitcnt vmcnt(8) lgkmcnt(0)" ::: "memory");   \
            __builtin_amdgcn_s_barrier();                                 \
            __builtin_amdgcn_sched_barrier(0);                            \
            GLL_A(ASL0, t+1)                                              \
            MFMA_PH(ASL1, BSL1)                                           \
        }                                                                 \
    }                                                                     \
    {   /* final phase t = KT-1 (odd) */                                  \
        CVTWRB(BSL1)                                                      \
        asm volatile("s_waitcnt vmcnt(0) lgkmcnt(0)" ::: "memory");       \
        __builtin_amdgcn_s_barrier();                                     \
        __builtin_amdgcn_sched_barrier(0);                                \
        MFMA_PH(ASL1, BSL1)                                               \
    }

// ---------------- GEMM1: h = gelu(gather(x16) @ W1[k] + b1[k]) ----------------
__global__ __launch_bounds__(256, 2) void k_gemm1(
    const unsigned short* __restrict__ x16, const float* __restrict__ W1,
    const float* __restrict__ b1, const int* __restrict__ wsi,
    unsigned short* __restrict__ hbuf, int pair_cap)
{
    __shared__ char lds[65536];
    __shared__ int stok[BM];
    const int* seg  = wsi + WS_SEG;
    const int* tk   = wsi + WS_TILEK;
    const int* tr   = wsi + WS_TILER;
    const int* ptok = wsi + WS_PTOK;
    int ntm = wsi[WS_NTILES];
    int nwork = ntm * (NF / BN);
    int tid  = threadIdx.x;
    int L    = tid & 63;
    int wv   = tid >> 6;
    int wr = wv >> 1, wc = wv & 1;
    int bu = tid >> 5, bg = tid & 31;          // B staging roles
    unsigned l31 = (unsigned)(L & 31);
    unsigned arow0 = (unsigned)(wr*64) + l31;
    unsigned arow1 = arow0 + 32u;
    unsigned bcol0 = BSL0*0 + (unsigned)(wc*64) + l31;   // col index only
    unsigned bcol1 = bcol0 + 32u;
    unsigned ah16 = (unsigned)((L >> 5) * 16);
    unsigned axr  = (unsigned)((L & 7) << 4);
    unsigned bxr  = ((l31 >> 1) & 7u) << 4;
    int asw8 = ((L & 7) ^ (L >> 3)) * 8;       // pre-swizzled source (f16 units)
    int srow = L >> 3;

    XCD_PART_LOOP(nwork){
        int widx = start_ + p_;
        int mt = widx % ntm;
        int ft = widx / ntm;
        int kexp = tk[mt];
        int row0 = tr[mt];
        int nrows = min(BM, seg[kexp+1] - row0);
        int f0 = ft * BN;
        __syncthreads();
        if (tid < BM){
            int r = row0 + tid;
            stok[tid] = (tid < nrows && r < pair_cap) ? ptok[r] : ptok[row0];
        }
        __syncthreads();
        const unsigned short* asrc[4];
        #pragma unroll
        for (int c = 0; c < 4; c++)
            asrc[c] = x16 + (size_t)stok[(wv*4 + c)*8 + srow] * ND;
        const float* bsrc = W1 + (size_t)kexp*ND*NF + f0 + bg*4;
        f32x4 gb[8];
        PIPE_LOOP(NF)
        // epilogue
        const float* b1k = b1 + (size_t)kexp*NF;
        #pragma unroll
        for (int n = 0; n < 2; n++){
            int f = f0 + wc*64 + n*32 + (int)l31;
            float bv = b1k[f];
            #pragma unroll
            for (int m = 0; m < 2; m++){
                int rbase = wr*64 + m*32 + 4*(L>>5);
                const f32x16& a = (m==0) ? (n==0 ? acc00 : acc01) : (n==0 ? acc10 : acc11);
                #pragma unroll
                for (int rg = 0; rg < 16; rg++){
                    int row = rbase + (rg&3) + 8*(rg>>2);
                    if (row < nrows && row0 + row < pair_cap){
                        float v = gelu_exact(a[rg] + bv);
                        hbuf[(size_t)(row0+row)*NF + f] = (unsigned short)(pkrtz(v, 0.f) & 0xffffu);
                    }
                }
            }
        }
    }
}

// ---------------- GEMM2 (split-K): y += coef*(h @ W2[k] + b2[k]) ----------------
__global__ __launch_bounds__(256, 2) void k_gemm2(
    const unsigned short* __restrict__ hbuf, const float* __restrict__ W2,
    const float* __restrict__ b2, const int* __restrict__ wsi,
    const float* __restrict__ wsf, float* __restrict__ out, int pair_cap)
{
    __shared__ char lds[65536];
    __shared__ int stok[BM];
    __shared__ float scoef[BM];
    const int* seg  = wsi + WS_SEG;
    const int* tk   = wsi + WS_TILEK;
    const int* tr   = wsi + WS_TILER;
    const int* ptok = wsi + WS_PTOK;
    const float* pcoef = wsf + WS_PCOEF;
    int ntm = wsi[WS_NTILES];
    int nwork = ntm * (ND / BN) * SPLITK2;     // mt fastest, dt(8), sp(4)
    int tid  = threadIdx.x;
    int L    = tid & 63;
    int wv   = tid >> 6;
    int wr = wv >> 1, wc = wv & 1;
    int bu = tid >> 5, bg = tid & 31;
    unsigned l31 = (unsigned)(L & 31);
    unsigned arow0 = (unsigned)(wr*64) + l31;
    unsigned arow1 = arow0 + 32u;
    unsigned bcol0 = (unsigned)(wc*64) + l31;
    unsigned bcol1 = bcol0 + 32u;
    unsigned ah16 = (unsigned)((L >> 5) * 16);
    unsigned axr  = (unsigned)((L & 7) << 4);
    unsigned bxr  = ((l31 >> 1) & 7u) << 4;
    int asw8 = ((L & 7) ^ (L >> 3)) * 8;
    int srow = L >> 3;

    XCD_PART_LOOP(nwork){
        int widx = start_ + p_;
        int mt = widx % ntm;
        int rest = widx / ntm;
        int dt = rest & 7;
        int spk = rest >> 3;
        int kexp = tk[mt];
        int row0 = tr[mt];
        int nrows = min(BM, seg[kexp+1] - row0);
        int d0 = dt * BN;
        __syncthreads();
        if (tid < BM){
            int r = row0 + tid;
            bool v = (tid < nrows && r < pair_cap);
            stok[tid]  = v ? ptok[r] : 0;
            scoef[tid] = v ? pcoef[r] : 0.f;
        }
        __syncthreads();
        const unsigned short* asrc[4];
        #pragma unroll
        for (int c = 0; c < 4; c++){
            int rg = row0 + (wv*4 + c)*8 + srow;
            if (rg >= pair_cap) rg = pair_cap - 1;
            asrc[c] = hbuf + (size_t)rg*NF + spk*(NF/SPLITK2);
        }
        const float* bsrc = W2 + (size_t)kexp*NF*ND + (size_t)spk*(NF/SPLITK2)*ND + d0 + bg*4;
        f32x4 gb[8];
        PIPE_LOOP(ND)
        // epilogue
        const float* b2k = b2 + (size_t)kexp*ND;
        #pragma unroll
        for (int n = 0; n < 2; n++){
            int d = d0 + wc*64 + n*32 + (int)l31;
            float bv = (spk == 0) ? b2k[d] : 0.f;
            #pragma unroll
            for (int m = 0; m < 2; m++){
                int rbase = wr*64 + m*32 + 4*(L>>5);
                const f32x16& a = (m==0) ? (n==0 ? acc00 : acc01) : (n==0 ? acc10 : acc11);
                #pragma unroll
                for (int rg = 0; rg < 16; rg++){
                    int row = rbase + (rg&3) + 8*(rg>>2);
                    if (row < nrows && row0 + row < pair_cap){
                        float c = scoef[row];
                        atomicAdd(&out[(size_t)stok[row]*ND + d], c * (a[rg] + bv));
                    }
                }
            }
        }
    }
}

extern "C" void kernel_launch(void* const* d_in, const int* in_sizes, int n_in,
                              void* d_out, int out_size, void* d_ws, size_t ws_size,
                              hipStream_t stream)
{
    const float* x   = (const float*)d_in[0];
    const float* pl  = (const float*)d_in[1];
    const float* Wt  = (const float*)d_in[2];
    const float* Wgt = (const float*)d_in[3];
    const float* Wel = (const float*)d_in[4];
    const float* W1  = (const float*)d_in[5];
    const float* b1  = (const float*)d_in[6];
    const float* W2  = (const float*)d_in[7];
    const float* b2  = (const float*)d_in[8];
    float* out = (float*)d_out;
    int* wsi   = (int*)d_ws;
    float* wsf = (float*)d_ws;
    unsigned short* x16  = (unsigned short*)((char*)d_ws + (size_t)WS_X16*4);
    unsigned short* hbuf = (unsigned short*)((char*)d_ws + (size_t)WS_H*4);

    long long avail = (long long)ws_size - (long long)WS_H*4;
    long long cap = avail / ((long long)NF*2);
    if (cap > (long long)NTOK*NK) cap = (long long)NTOK*NK;
    if (cap < 0) cap = 0;
    int pair_cap = (int)cap;

    hipMemsetAsync(d_out, 0, (size_t)out_size*sizeof(float), stream);
    hipMemsetAsync(d_ws, 0, 32, stream);
    k_xcast<<<1024, 256, 0, stream>>>(x, x16);
    k_gating<<<NTOK, 256, 0, stream>>>(x, pl, Wt, Wgt, Wel, out, wsf + WS_COEF, wsi + WS_CNT);
    if (pair_cap > 0){
        k_scan<<<NK, 256, 0, stream>>>(wsf + WS_COEF, wsi, wsf, pair_cap);
        k_tiles<<<1, 64, 0, stream>>>(wsi, out, pair_cap);
        k_gemm1<<<2048, 256, 0, stream>>>(x16, W1, b1, wsi, hbuf, pair_cap);
        k_gemm2<<<2048, 256, 0, stream>>>(hbuf, W2, b2, wsi, wsf, out, pair_cap);
    }
}